// Round 2
// baseline (89211.908 us; speedup 1.0000x reference)
//
#include <hip/hip_runtime.h>
#include <hip/hip_cooperative_groups.h>
#include <math.h>

namespace cg = cooperative_groups;

#define PI_F 3.14159265358979323846f

// RK stage constants (precomputed in double, stored as float):
// beta[k], gdt[k]=GAMMA[k]*DT, mu[k]=0.5*DT*(ALPHA[k+1]-ALPHA[k])
__constant__ float c_beta[5] = {0.0f, -0.4178904745f, -1.192151694643f,
                                -1.697784692471f, -1.514183444257f};
__constant__ float c_gdt[5]  = {1.496590219993e-4f, 3.792103129999e-4f,
                                8.229550293869e-4f, 6.994504559488e-4f,
                                1.530572479681e-4f};
__constant__ float c_mu[5]   = {7.482951099965e-5f, 1.1037096768255e-4f,
                                1.2592740288505e-4f, 1.6801318377015e-4f,
                                2.08589346626e-5f};

struct SharedMem {
  float sAr[256], sAi[256], sBr[256], sBi[256];
  float twr[128], twi[128];
  float t0r[387], t0i[387], t1r[387], t1i[387];   // [129][2] tiles, stride 3
};

// ---------------------------------------------------------------------------
// 256-point Stockham radix-2 FFT in LDS. 256 threads, auto-sorting.
// Result ends in (sAr, sAi). No scaling either direction.
// ---------------------------------------------------------------------------
template<bool INVERSE>
__device__ __forceinline__ void fft256(SharedMem& sh, int t)
{
  float *sr = sh.sAr, *si = sh.sAi, *dr = sh.sBr, *di = sh.sBi;
#pragma unroll
  for (int s = 0; s < 8; ++s) {
    __syncthreads();
    int m  = 1 << s;
    int k  = t & (m - 1);
    int jm = (t >> (s + 1)) << s;
    int i0 = k + jm;
    float c0r = sr[i0],       c0i = si[i0];
    float c1r = sr[i0 + 128], c1i = si[i0 + 128];
    float orr, oii;
    if ((t >> s) & 1) {
      float xr = c0r - c1r, xi = c0i - c1i;
      float wr = sh.twr[jm];
      float wi = INVERSE ? -sh.twi[jm] : sh.twi[jm];
      orr = xr * wr - xi * wi;
      oii = xr * wi + xi * wr;
    } else {
      orr = c0r + c1r;
      oii = c0i + c1i;
    }
    dr[t] = orr; di[t] = oii;
    float* tp;
    tp = sr; sr = dr; dr = tp;
    tp = si; si = di; di = tp;
  }
  __syncthreads();
}

// ---------------------------------------------------------------------------
// Layouts (float2):
//   u, h : [b][ky][kx]     8*129*256
//   G    : [f][b][ky][x]   4*8*129*256   (f: 0=vx 1=vy 2=gx 3=gy)
//   NL1  : [b][ky][x]      8*86*256
//   rec  : [r][b][ky][kx]  3*8*129*256
// ---------------------------------------------------------------------------

// real-space item: 2 x-columns (x0, x0+1) of batch b.
__device__ __forceinline__ void real_item(SharedMem& sh, int t, int b, int x0,
    const float2* __restrict__ G, float2* __restrict__ NL1)
{
  for (int i = t; i < 258; i += 256) {
    int ky = i >> 1, xl = i & 1;
    float2 a = G[(((size_t)0 * 8 + b) * 129 + ky) * 256 + x0 + xl];
    float2 c = G[(((size_t)1 * 8 + b) * 129 + ky) * 256 + x0 + xl];
    sh.t0r[ky * 3 + xl] = a.x; sh.t0i[ky * 3 + xl] = a.y;
    sh.t1r[ky * 3 + xl] = c.x; sh.t1i[ky * 3 + xl] = c.y;
  }
  __syncthreads();
  const int  kk    = (t <= 128) ? t : 256 - t;
  const bool lower = (t <= 128);
  float vxr[2], vyr[2];
#pragma unroll
  for (int xl = 0; xl < 2; ++xl) {
    float ar = sh.t0r[kk * 3 + xl], ai = sh.t0i[kk * 3 + xl];
    float br = sh.t1r[kk * 3 + xl], bi = sh.t1i[kk * 3 + xl];
    sh.sAr[t] = lower ? (ar - bi) : (ar + bi);   // Z = Hvx + i*Hvy
    sh.sAi[t] = lower ? (ai + br) : (br - ai);
    fft256<true>(sh, t);
    vxr[xl] = sh.sAr[t]; vyr[xl] = sh.sAi[t];
  }
  __syncthreads();
  for (int i = t; i < 258; i += 256) {
    int ky = i >> 1, xl = i & 1;
    float2 a = G[(((size_t)2 * 8 + b) * 129 + ky) * 256 + x0 + xl];
    float2 c = G[(((size_t)3 * 8 + b) * 129 + ky) * 256 + x0 + xl];
    sh.t0r[ky * 3 + xl] = a.x; sh.t0i[ky * 3 + xl] = a.y;
    sh.t1r[ky * 3 + xl] = c.x; sh.t1i[ky * 3 + xl] = c.y;
  }
  __syncthreads();
  float nl[2];
#pragma unroll
  for (int xl = 0; xl < 2; ++xl) {
    float ar = sh.t0r[kk * 3 + xl], ai = sh.t0i[kk * 3 + xl];
    float br = sh.t1r[kk * 3 + xl], bi = sh.t1i[kk * 3 + xl];
    sh.sAr[t] = lower ? (ar - bi) : (ar + bi);   // Z = Hgx + i*Hgy
    sh.sAi[t] = lower ? (ai + br) : (br - ai);
    fft256<true>(sh, t);
    float gx = sh.sAr[t], gy = sh.sAi[t];
    nl[xl] = -(vxr[xl] * gx + vyr[xl] * gy);
  }
  // paired forward rfft of the two real rows
  sh.sAr[t] = nl[0]; sh.sAi[t] = nl[1];
  fft256<false>(sh, t);
  if (t <= 85) {
    int mI = (256 - t) & 255;
    float zr = sh.sAr[t],  zi = sh.sAi[t];
    float wr = sh.sAr[mI], wi = sh.sAi[mI];
    float f0r = 0.5f * (zr + wr), f0i = 0.5f * (zi - wi);
    float f1r = 0.5f * (zi + wi), f1i = 0.5f * (wr - zr);
    NL1[((size_t)b * 86 + t) * 256 + x0]     = make_float2(f0r, f0i);
    NL1[((size_t)b * 86 + t) * 256 + x0 + 1] = make_float2(f1r, f1i);
  }
}

// spectral item: one (b, ky) row. Fwd FFT of NL, RK update, 4 inverse FFTs -> G.
__device__ __forceinline__ void spectral_item(SharedMem& sh, int t, int b, int ky,
    const float2* __restrict__ NL1, float2* __restrict__ u, float2* __restrict__ h,
    float2* __restrict__ G, float2* __restrict__ rec,
    float beta, float gdt, float mu, bool doUpdate, int recIdx)
{
  const size_t row = ((size_t)b * 129 + ky) * 256;
  float2 uu = u[row + t];
  float ur = uu.x, ui = uu.y;
  const int jx = (t < 128) ? t : t - 256;
  const float k2 = (float)(jx * jx + ky * ky);

  if (doUpdate) {
    float advr = 0.0f, advi = 0.0f;
    if (ky <= 85) {                                  // block-uniform branch
      float2 nv = NL1[((size_t)b * 86 + ky) * 256 + t];
      sh.sAr[t] = nv.x; sh.sAi[t] = nv.y;
      fft256<false>(sh, t);
      if (t < 85 || t >= 171) { advr = sh.sAr[t]; advi = sh.sAi[t]; }
    }
    if (t == 0 && ky == 4) {                         // forcing f_hat
      float s_, c_;
      __sincosf(PI_F / 64.0f, &s_, &c_);
      advr -= 131072.0f * c_;
      advi -= 131072.0f * s_;
    }
    float hr = advr, hi = advi;
    if (beta != 0.0f) {
      float2 hh = h[row + t];
      hr += beta * hh.x; hi += beta * hh.y;
    }
    const float lin  = -0.001f * k2 - 0.1f;
    const float anum = 1.0f + mu * lin;
    const float invd = 1.0f / (1.0f - mu * lin);
    ur = (ur * anum + gdt * hr) * invd;
    ui = (ui * anum + gdt * hi) * invd;
    u[row + t] = make_float2(ur, ui);
    h[row + t] = make_float2(hr, hi);
    if (recIdx >= 0)
      rec[((size_t)recIdx * 8 + b) * (129 * 256) + (size_t)ky * 256 + t] = make_float2(ur, ui);
  }

  const float NRM = 1.0f / 65536.0f;
  const float inv_lapnz = (k2 == 0.0f) ? 1.0f : (-1.0f / k2);
  const float urN = ur * NRM, uiN = ui * NRM;
  const float psr = -urN * inv_lapnz, psi_ = -uiN * inv_lapnz;
  const float fjx = (float)jx, fjy = (float)ky;

  sh.sAr[t] = -fjy * psi_; sh.sAi[t] = fjy * psr;        // vx_hat = i*ky*psi
  fft256<true>(sh, t);
  G[(((size_t)0 * 8 + b) * 129 + ky) * 256 + t] = make_float2(sh.sAr[t], sh.sAi[t]);
  sh.sAr[t] = fjx * psi_; sh.sAi[t] = -fjx * psr;        // vy_hat = -i*kx*psi
  fft256<true>(sh, t);
  G[(((size_t)1 * 8 + b) * 129 + ky) * 256 + t] = make_float2(sh.sAr[t], sh.sAi[t]);
  sh.sAr[t] = -fjx * uiN; sh.sAi[t] = fjx * urN;         // gx_hat = i*kx*u
  fft256<true>(sh, t);
  G[(((size_t)2 * 8 + b) * 129 + ky) * 256 + t] = make_float2(sh.sAr[t], sh.sAi[t]);
  sh.sAr[t] = -fjy * uiN; sh.sAi[t] = fjy * urN;         // gy_hat = i*ky*u
  fft256<true>(sh, t);
  G[(((size_t)3 * 8 + b) * 129 + ky) * 256 + t] = make_float2(sh.sAr[t], sh.sAi[t]);
}

// ---------------------------------------------------------------------------
// Persistent cooperative kernel: whole solve in one dispatch.
// ---------------------------------------------------------------------------
__global__ __launch_bounds__(256, 4) void k_persist(
    const float* __restrict__ vort, float* __restrict__ out,
    float2* __restrict__ u, float2* __restrict__ h,
    float2* __restrict__ G, float2* __restrict__ NL1, float2* __restrict__ rec)
{
  cg::grid_group grid = cg::this_grid();
  const int t   = threadIdx.x;
  const int blk = blockIdx.x;
  const int NBg = gridDim.x;
  __shared__ SharedMem sh;

  if (t < 128) {
    float s_, c_;
    __sincosf(-(2.0f * PI_F / 256.0f) * (float)t, &s_, &c_);
    sh.twr[t] = c_; sh.twi[t] = s_;
  }
  // (fft256's leading barrier makes twiddles visible before first use)

  // ---- init: rfft along y for each (b, x); W1 aliases G ----
  for (int w = blk; w < 2048; w += NBg) {
    int b = w >> 8, x = w & 255;
    sh.sAr[t] = vort[((size_t)b * 256 + x) * 256 + t];
    sh.sAi[t] = 0.0f;
    fft256<false>(sh, t);
    if (t < 129) G[((size_t)b * 129 + t) * 256 + x] = make_float2(sh.sAr[t], sh.sAi[t]);
  }
  grid.sync();

  // ---- init: complex FFT along x for each (b, ky): W1(=G) -> u ----
  for (int w = blk; w < 1032; w += NBg) {
    int b = w / 129, ky = w % 129;
    float2 v = G[((size_t)b * 129 + ky) * 256 + t];
    sh.sAr[t] = v.x; sh.sAi[t] = v.y;
    fft256<false>(sh, t);
    u[((size_t)b * 129 + ky) * 256 + t] = make_float2(sh.sAr[t], sh.sAi[t]);
  }
  grid.sync();

  // ---- prepare G from initial u (no update) ----
  for (int w = blk; w < 1032; w += NBg) {
    int b = w / 129, ky = w % 129;
    spectral_item(sh, t, b, ky, NL1, u, h, G, rec, 0.f, 0.f, 0.f, false, -1);
  }

  // ---- main loop: 90 steps x 5 RK stages ----
  for (int step = 1; step <= 90; ++step) {
    for (int k = 0; k < 5; ++k) {
      grid.sync();
      for (int w = blk; w < 1024; w += NBg) {
        int b = w >> 7, xq = w & 127;
        real_item(sh, t, b, xq * 2, G, NL1);
      }
      grid.sync();
      const float beta = c_beta[k], gdt = c_gdt[k], mu = c_mu[k];
      const int recIdx = (k == 4 && step % 30 == 0) ? (step / 30 - 1) : -1;
      for (int w = blk; w < 1032; w += NBg) {
        int b = w / 129, ky = w % 129;
        spectral_item(sh, t, b, ky, NL1, u, h, G, rec, beta, gdt, mu, true, recIdx);
      }
    }
  }
  grid.sync();

  // ---- final: inverse col FFT of records (rec -> G scratch) ----
  for (int w = blk; w < 3096; w += NBg) {
    int r = w / 1032, rem = w - r * 1032;
    int b = rem / 129, ky = rem % 129;
    const size_t row = (((size_t)r * 8 + b) * 129 + ky) * 256;
    float2 v = rec[row + t];
    sh.sAr[t] = v.x; sh.sAi[t] = v.y;
    fft256<true>(sh, t);
    G[row + t] = make_float2(sh.sAr[t], sh.sAi[t]);
  }
  grid.sync();

  // ---- final: paired hermitian inverse row FFT -> real output ----
  const float NRM = 1.0f / 65536.0f;
  for (int w = blk; w < 3072; w += NBg) {
    int r = w / 1024, rem = w - r * 1024;
    int b = rem >> 7, xq = rem & 127;
    int x0 = xq * 2;
    for (int i = t; i < 258; i += 256) {
      int ky = i >> 1, xl = i & 1;
      float2 a = G[(((size_t)r * 8 + b) * 129 + ky) * 256 + x0 + xl];
      sh.t0r[ky * 3 + xl] = a.x; sh.t0i[ky * 3 + xl] = a.y;
    }
    __syncthreads();
    const int  kk    = (t <= 128) ? t : 256 - t;
    const bool lower = (t <= 128);
    float ar = sh.t0r[kk * 3 + 0], ai = sh.t0i[kk * 3 + 0];
    float br = sh.t0r[kk * 3 + 1], bi = sh.t0i[kk * 3 + 1];
    sh.sAr[t] = lower ? (ar - bi) : (ar + bi);
    sh.sAi[t] = lower ? (ai + br) : (br - ai);
    fft256<true>(sh, t);
    out[((((size_t)r * 8 + b) * 256) + x0) * 256 + t]     = sh.sAr[t] * NRM;
    out[((((size_t)r * 8 + b) * 256) + x0 + 1) * 256 + t] = sh.sAi[t] * NRM;
    __syncthreads();   // tiles reused next iteration
  }
}

// ---------------------------------------------------------------------------
extern "C" void kernel_launch(void* const* d_in, const int* in_sizes, int n_in,
                              void* d_out, int out_size, void* d_ws, size_t ws_size,
                              hipStream_t stream)
{
  const float* vort = (const float*)d_in[0];
  float* out = (float*)d_out;

  // workspace carve-up (float2 units); total ~19.5 MiB
  float2* base = (float2*)d_ws;
  float2* u    = base;                 // 8*129*256   = 264192
  float2* h    = u + 264192;           // 264192
  float2* G    = h + 264192;           // 4*8*129*256 = 1056768
  float2* NL1  = G + 1056768;          // 8*86*256    = 176128
  float2* rec  = NL1 + 176128;         // 3*8*129*256 = 792576

  int maxPerCU = 0;
  hipOccupancyMaxActiveBlocksPerMultiprocessor(&maxPerCU, k_persist, 256, 0);
  int NBg = maxPerCU * 256;            // 256 CUs on MI355X
  if (NBg > 1024) NBg = 1024;
  if (NBg < 256)  NBg = 256;           // defensive; launch_bounds guarantees >=4/CU

  void* args[] = {(void*)&vort, (void*)&out, (void*)&u, (void*)&h,
                  (void*)&G, (void*)&NL1, (void*)&rec};
  hipLaunchCooperativeKernel(k_persist, dim3(NBg), dim3(256), args, 0, stream);
}

// Round 3
// 44474.026 us; speedup vs baseline: 2.0059x; 2.0059x over previous
//
#include <hip/hip_runtime.h>
#include <math.h>

#define PI_F 3.14159265358979323846f

// RK stage constants: beta[k], gdt[k]=GAMMA[k]*DT, mu[k]=0.5*DT*(ALPHA[k+1]-ALPHA[k])
__constant__ float c_beta[5] = {0.0f, -0.4178904745f, -1.192151694643f,
                                -1.697784692471f, -1.514183444257f};
__constant__ float c_gdt[5]  = {1.496590219993e-4f, 3.792103129999e-4f,
                                8.229550293869e-4f, 6.994504559488e-4f,
                                1.530572479681e-4f};
__constant__ float c_mu[5]   = {7.482951099965e-5f, 1.1037096768255e-4f,
                                1.2592740288505e-4f, 1.6801318377015e-4f,
                                2.08589346626e-5f};

struct SharedMem {
  float sAr[256], sAi[256], sBr[256], sBi[256];
  float twr[128], twi[128];
  float t0r[387], t0i[387], t1r[387], t1i[387];   // [129][2] tiles, stride 3
};

// ---------------------------------------------------------------------------
// Two-level grid barrier. bar[0] = root; bar[64 + l*32] = leaf l (64 leaves,
// 128B apart). Monotonic generation counts; memory zeroed before launch via
// hipMemsetAsync. NBg must be a multiple of 64. ~16 parallel leaf atomics +
// 64 root atomics instead of CG's 1024 serialized same-address atomics.
// ---------------------------------------------------------------------------
__device__ __forceinline__ void gbar(int* bar, int blk, int NBg, int gen)
{
  __syncthreads();                       // all block threads done; stores drained to L2
  if (threadIdx.x == 0) {
    int* leaf = bar + 64 + (blk & 63) * 32;
    const int bpl = NBg >> 6;            // blocks per leaf
    // release: write back this XCD's L2 so data is device-visible
    int c = __hip_atomic_fetch_add(leaf, 1, __ATOMIC_RELEASE, __HIP_MEMORY_SCOPE_AGENT);
    if (c == gen * bpl - 1)
      __hip_atomic_fetch_add(bar, 1, __ATOMIC_RELEASE, __HIP_MEMORY_SCOPE_AGENT);
    while (__hip_atomic_load(bar, __ATOMIC_RELAXED, __HIP_MEMORY_SCOPE_AGENT) < gen * 64)
      __builtin_amdgcn_s_sleep(2);
    // acquire: invalidate stale cache lines before post-barrier reads
    (void)__hip_atomic_load(bar, __ATOMIC_ACQUIRE, __HIP_MEMORY_SCOPE_AGENT);
  }
  __syncthreads();
}

// ---------------------------------------------------------------------------
// 256-point Stockham radix-2 FFT in LDS. 256 threads, auto-sorting.
// Result ends in (sAr, sAi). No scaling either direction.
// ---------------------------------------------------------------------------
template<bool INVERSE>
__device__ __forceinline__ void fft256(SharedMem& sh, int t)
{
  float *sr = sh.sAr, *si = sh.sAi, *dr = sh.sBr, *di = sh.sBi;
#pragma unroll
  for (int s = 0; s < 8; ++s) {
    __syncthreads();
    int m  = 1 << s;
    int k  = t & (m - 1);
    int jm = (t >> (s + 1)) << s;
    int i0 = k + jm;
    float c0r = sr[i0],       c0i = si[i0];
    float c1r = sr[i0 + 128], c1i = si[i0 + 128];
    float orr, oii;
    if ((t >> s) & 1) {
      float xr = c0r - c1r, xi = c0i - c1i;
      float wr = sh.twr[jm];
      float wi = INVERSE ? -sh.twi[jm] : sh.twi[jm];
      orr = xr * wr - xi * wi;
      oii = xr * wi + xi * wr;
    } else {
      orr = c0r + c1r;
      oii = c0i + c1i;
    }
    dr[t] = orr; di[t] = oii;
    float* tp;
    tp = sr; sr = dr; dr = tp;
    tp = si; si = di; di = tp;
  }
  __syncthreads();
}

// ---------------------------------------------------------------------------
// Layouts (float2):
//   u, h : [b][ky][kx]     8*129*256
//   G    : [f][b][ky][x]   4*8*129*256   (f: 0=vx 1=vy 2=gx 3=gy)
//   NL1  : [b][ky][x]      8*86*256
//   rec  : [r][b][ky][kx]  3*8*129*256
// ---------------------------------------------------------------------------

__device__ __forceinline__ void real_item(SharedMem& sh, int t, int b, int x0,
    const float2* __restrict__ G, float2* __restrict__ NL1)
{
  for (int i = t; i < 258; i += 256) {
    int ky = i >> 1, xl = i & 1;
    float2 a = G[(((size_t)0 * 8 + b) * 129 + ky) * 256 + x0 + xl];
    float2 c = G[(((size_t)1 * 8 + b) * 129 + ky) * 256 + x0 + xl];
    sh.t0r[ky * 3 + xl] = a.x; sh.t0i[ky * 3 + xl] = a.y;
    sh.t1r[ky * 3 + xl] = c.x; sh.t1i[ky * 3 + xl] = c.y;
  }
  __syncthreads();
  const int  kk    = (t <= 128) ? t : 256 - t;
  const bool lower = (t <= 128);
  float vxr[2], vyr[2];
#pragma unroll
  for (int xl = 0; xl < 2; ++xl) {
    float ar = sh.t0r[kk * 3 + xl], ai = sh.t0i[kk * 3 + xl];
    float br = sh.t1r[kk * 3 + xl], bi = sh.t1i[kk * 3 + xl];
    sh.sAr[t] = lower ? (ar - bi) : (ar + bi);   // Z = Hvx + i*Hvy
    sh.sAi[t] = lower ? (ai + br) : (br - ai);
    fft256<true>(sh, t);
    vxr[xl] = sh.sAr[t]; vyr[xl] = sh.sAi[t];
  }
  __syncthreads();
  for (int i = t; i < 258; i += 256) {
    int ky = i >> 1, xl = i & 1;
    float2 a = G[(((size_t)2 * 8 + b) * 129 + ky) * 256 + x0 + xl];
    float2 c = G[(((size_t)3 * 8 + b) * 129 + ky) * 256 + x0 + xl];
    sh.t0r[ky * 3 + xl] = a.x; sh.t0i[ky * 3 + xl] = a.y;
    sh.t1r[ky * 3 + xl] = c.x; sh.t1i[ky * 3 + xl] = c.y;
  }
  __syncthreads();
  float nl[2];
#pragma unroll
  for (int xl = 0; xl < 2; ++xl) {
    float ar = sh.t0r[kk * 3 + xl], ai = sh.t0i[kk * 3 + xl];
    float br = sh.t1r[kk * 3 + xl], bi = sh.t1i[kk * 3 + xl];
    sh.sAr[t] = lower ? (ar - bi) : (ar + bi);   // Z = Hgx + i*Hgy
    sh.sAi[t] = lower ? (ai + br) : (br - ai);
    fft256<true>(sh, t);
    float gx = sh.sAr[t], gy = sh.sAi[t];
    nl[xl] = -(vxr[xl] * gx + vyr[xl] * gy);
  }
  sh.sAr[t] = nl[0]; sh.sAi[t] = nl[1];
  fft256<false>(sh, t);
  if (t <= 85) {
    int mI = (256 - t) & 255;
    float zr = sh.sAr[t],  zi = sh.sAi[t];
    float wr = sh.sAr[mI], wi = sh.sAi[mI];
    float f0r = 0.5f * (zr + wr), f0i = 0.5f * (zi - wi);
    float f1r = 0.5f * (zi + wi), f1i = 0.5f * (wr - zr);
    NL1[((size_t)b * 86 + t) * 256 + x0]     = make_float2(f0r, f0i);
    NL1[((size_t)b * 86 + t) * 256 + x0 + 1] = make_float2(f1r, f1i);
  }
}

__device__ __forceinline__ void spectral_item(SharedMem& sh, int t, int b, int ky,
    const float2* __restrict__ NL1, float2* __restrict__ u, float2* __restrict__ h,
    float2* __restrict__ G, float2* __restrict__ rec,
    float beta, float gdt, float mu, bool doUpdate, int recIdx)
{
  const size_t row = ((size_t)b * 129 + ky) * 256;
  float2 uu = u[row + t];
  float ur = uu.x, ui = uu.y;
  const int jx = (t < 128) ? t : t - 256;
  const float k2 = (float)(jx * jx + ky * ky);

  if (doUpdate) {
    float advr = 0.0f, advi = 0.0f;
    if (ky <= 85) {
      float2 nv = NL1[((size_t)b * 86 + ky) * 256 + t];
      sh.sAr[t] = nv.x; sh.sAi[t] = nv.y;
      fft256<false>(sh, t);
      if (t < 85 || t >= 171) { advr = sh.sAr[t]; advi = sh.sAi[t]; }
    }
    if (t == 0 && ky == 4) {
      float s_, c_;
      __sincosf(PI_F / 64.0f, &s_, &c_);
      advr -= 131072.0f * c_;
      advi -= 131072.0f * s_;
    }
    float hr = advr, hi = advi;
    if (beta != 0.0f) {
      float2 hh = h[row + t];
      hr += beta * hh.x; hi += beta * hh.y;
    }
    const float lin  = -0.001f * k2 - 0.1f;
    const float anum = 1.0f + mu * lin;
    const float invd = 1.0f / (1.0f - mu * lin);
    ur = (ur * anum + gdt * hr) * invd;
    ui = (ui * anum + gdt * hi) * invd;
    u[row + t] = make_float2(ur, ui);
    h[row + t] = make_float2(hr, hi);
    if (recIdx >= 0)
      rec[((size_t)recIdx * 8 + b) * (129 * 256) + (size_t)ky * 256 + t] = make_float2(ur, ui);
  }

  const float NRM = 1.0f / 65536.0f;
  const float inv_lapnz = (k2 == 0.0f) ? 1.0f : (-1.0f / k2);
  const float urN = ur * NRM, uiN = ui * NRM;
  const float psr = -urN * inv_lapnz, psi_ = -uiN * inv_lapnz;
  const float fjx = (float)jx, fjy = (float)ky;

  sh.sAr[t] = -fjy * psi_; sh.sAi[t] = fjy * psr;        // vx_hat = i*ky*psi
  fft256<true>(sh, t);
  G[(((size_t)0 * 8 + b) * 129 + ky) * 256 + t] = make_float2(sh.sAr[t], sh.sAi[t]);
  sh.sAr[t] = fjx * psi_; sh.sAi[t] = -fjx * psr;        // vy_hat = -i*kx*psi
  fft256<true>(sh, t);
  G[(((size_t)1 * 8 + b) * 129 + ky) * 256 + t] = make_float2(sh.sAr[t], sh.sAi[t]);
  sh.sAr[t] = -fjx * uiN; sh.sAi[t] = fjx * urN;         // gx_hat = i*kx*u
  fft256<true>(sh, t);
  G[(((size_t)2 * 8 + b) * 129 + ky) * 256 + t] = make_float2(sh.sAr[t], sh.sAi[t]);
  sh.sAr[t] = -fjy * uiN; sh.sAi[t] = fjy * urN;         // gy_hat = i*ky*u
  fft256<true>(sh, t);
  G[(((size_t)3 * 8 + b) * 129 + ky) * 256 + t] = make_float2(sh.sAr[t], sh.sAi[t]);
}

// ---------------------------------------------------------------------------
// Persistent kernel: whole solve in one dispatch, custom tree barrier.
// ---------------------------------------------------------------------------
__global__ __launch_bounds__(256, 4) void k_persist(
    const float* __restrict__ vort, float* __restrict__ out,
    float2* __restrict__ u, float2* __restrict__ h,
    float2* __restrict__ G, float2* __restrict__ NL1, float2* __restrict__ rec,
    int* __restrict__ bar)
{
  const int t   = threadIdx.x;
  const int blk = blockIdx.x;
  const int NBg = gridDim.x;
  int gen = 0;
  __shared__ SharedMem sh;

  if (t < 128) {
    float s_, c_;
    __sincosf(-(2.0f * PI_F / 256.0f) * (float)t, &s_, &c_);
    sh.twr[t] = c_; sh.twi[t] = s_;
  }

  // ---- init: rfft along y for each (b, x); W1 aliases G ----
  for (int w = blk; w < 2048; w += NBg) {
    int b = w >> 8, x = w & 255;
    sh.sAr[t] = vort[((size_t)b * 256 + x) * 256 + t];
    sh.sAi[t] = 0.0f;
    fft256<false>(sh, t);
    if (t < 129) G[((size_t)b * 129 + t) * 256 + x] = make_float2(sh.sAr[t], sh.sAi[t]);
  }
  gbar(bar, blk, NBg, ++gen);

  // ---- init: complex FFT along x for each (b, ky): W1(=G) -> u ----
  for (int w = blk; w < 1032; w += NBg) {
    int b = w / 129, ky = w % 129;
    float2 v = G[((size_t)b * 129 + ky) * 256 + t];
    sh.sAr[t] = v.x; sh.sAi[t] = v.y;
    fft256<false>(sh, t);
    u[((size_t)b * 129 + ky) * 256 + t] = make_float2(sh.sAr[t], sh.sAi[t]);
  }
  gbar(bar, blk, NBg, ++gen);

  // ---- prepare G from initial u (no update) ----
  for (int w = blk; w < 1032; w += NBg) {
    int b = w / 129, ky = w % 129;
    spectral_item(sh, t, b, ky, NL1, u, h, G, rec, 0.f, 0.f, 0.f, false, -1);
  }

  // ---- main loop: 90 steps x 5 RK stages ----
  for (int step = 1; step <= 90; ++step) {
    for (int k = 0; k < 5; ++k) {
      gbar(bar, blk, NBg, ++gen);
      for (int w = blk; w < 1024; w += NBg) {
        int b = w >> 7, xq = w & 127;
        real_item(sh, t, b, xq * 2, G, NL1);
      }
      gbar(bar, blk, NBg, ++gen);
      const float beta = c_beta[k], gdt = c_gdt[k], mu = c_mu[k];
      const int recIdx = (k == 4 && step % 30 == 0) ? (step / 30 - 1) : -1;
      for (int w = blk; w < 1032; w += NBg) {
        int b = w / 129, ky = w % 129;
        spectral_item(sh, t, b, ky, NL1, u, h, G, rec, beta, gdt, mu, true, recIdx);
      }
    }
  }
  gbar(bar, blk, NBg, ++gen);

  // ---- final: inverse col FFT of records (rec -> G scratch) ----
  for (int w = blk; w < 3096; w += NBg) {
    int r = w / 1032, rem = w - r * 1032;
    int b = rem / 129, ky = rem % 129;
    const size_t row = (((size_t)r * 8 + b) * 129 + ky) * 256;
    float2 v = rec[row + t];
    sh.sAr[t] = v.x; sh.sAi[t] = v.y;
    fft256<true>(sh, t);
    G[row + t] = make_float2(sh.sAr[t], sh.sAi[t]);
  }
  gbar(bar, blk, NBg, ++gen);

  // ---- final: paired hermitian inverse row FFT -> real output ----
  const float NRM = 1.0f / 65536.0f;
  for (int w = blk; w < 3072; w += NBg) {
    int r = w / 1024, rem = w - r * 1024;
    int b = rem >> 7, xq = rem & 127;
    int x0 = xq * 2;
    for (int i = t; i < 258; i += 256) {
      int ky = i >> 1, xl = i & 1;
      float2 a = G[(((size_t)r * 8 + b) * 129 + ky) * 256 + x0 + xl];
      sh.t0r[ky * 3 + xl] = a.x; sh.t0i[ky * 3 + xl] = a.y;
    }
    __syncthreads();
    const int  kk    = (t <= 128) ? t : 256 - t;
    const bool lower = (t <= 128);
    float ar = sh.t0r[kk * 3 + 0], ai = sh.t0i[kk * 3 + 0];
    float br = sh.t0r[kk * 3 + 1], bi = sh.t0i[kk * 3 + 1];
    sh.sAr[t] = lower ? (ar - bi) : (ar + bi);
    sh.sAi[t] = lower ? (ai + br) : (br - ai);
    fft256<true>(sh, t);
    out[((((size_t)r * 8 + b) * 256) + x0) * 256 + t]     = sh.sAr[t] * NRM;
    out[((((size_t)r * 8 + b) * 256) + x0 + 1) * 256 + t] = sh.sAi[t] * NRM;
    __syncthreads();
  }
}

// ---------------------------------------------------------------------------
extern "C" void kernel_launch(void* const* d_in, const int* in_sizes, int n_in,
                              void* d_out, int out_size, void* d_ws, size_t ws_size,
                              hipStream_t stream)
{
  const float* vort = (const float*)d_in[0];
  float* out = (float*)d_out;

  // workspace carve-up (float2 units); total ~19.5 MiB + 8.4KB barrier
  float2* base = (float2*)d_ws;
  float2* u    = base;                 // 8*129*256   = 264192
  float2* h    = u + 264192;           // 264192
  float2* G    = h + 264192;           // 4*8*129*256 = 1056768
  float2* NL1  = G + 1056768;          // 8*86*256    = 176128
  float2* rec  = NL1 + 176128;         // 3*8*129*256 = 792576
  int*    bar  = (int*)(rec + 792576); // 64 + 64*32 ints

  // zero barrier state before every run (capture-legal)
  hipMemsetAsync(bar, 0, (64 + 64 * 32) * sizeof(int), stream);

  int maxPerCU = 0;
  hipOccupancyMaxActiveBlocksPerMultiprocessor(&maxPerCU, k_persist, 256, 0);
  int NBg = maxPerCU * 256;            // 256 CUs on MI355X
  if (NBg > 1024) NBg = 1024;
  NBg &= ~63;                          // multiple of 64 for the tree barrier
  if (NBg < 256)  NBg = 256;

  void* args[] = {(void*)&vort, (void*)&out, (void*)&u, (void*)&h,
                  (void*)&G, (void*)&NL1, (void*)&rec, (void*)&bar};
  hipLaunchCooperativeKernel(k_persist, dim3(NBg), dim3(256), args, 0, stream);
}

// Round 5
// 27675.677 us; speedup vs baseline: 3.2235x; 1.6070x over previous
//
#include <hip/hip_runtime.h>
#include <math.h>

#define PI_F 3.14159265358979323846f

// RK stage constants: beta[k], gdt[k]=GAMMA[k]*DT, mu[k]=0.5*DT*(ALPHA[k+1]-ALPHA[k])
__constant__ float c_beta[5] = {0.0f, -0.4178904745f, -1.192151694643f,
                                -1.697784692471f, -1.514183444257f};
__constant__ float c_gdt[5]  = {1.496590219993e-4f, 3.792103129999e-4f,
                                8.229550293869e-4f, 6.994504559488e-4f,
                                1.530572479681e-4f};
__constant__ float c_mu[5]   = {7.482951099965e-5f, 1.1037096768255e-4f,
                                1.2592740288505e-4f, 1.6801318377015e-4f,
                                2.08589346626e-5f};

struct SharedMem {
  float sAr[256], sAi[256], sBr[256], sBi[256];
  float twr[128], twi[128];
  float t0r[387], t0i[387], t1r[387], t1i[387];   // [129][2] tiles, stride 3
};

// ---------------------------------------------------------------------------
// Per-GROUP barrier (group g = blocks with blockIdx%8==g; gsz blocks/group,
// 8 subleaves of bps=gsz/8 blocks). Lines:
//   A[g][s] : arrival counters (bps adders each)      lines 0..63
//   R[g]    : group root (8 subleaf winners)          lines 64..71
//   F[g][s] : release flags, polled by bps blocks     lines 72..135
// Monotonic generations; bar zeroed pre-launch via hipMemsetAsync.
// Agent-scope release/acquire gives cross-XCD visibility (wbL2/invL2).
// ---------------------------------------------------------------------------
__device__ __forceinline__ void group_bar(int* bar, int g, int wi, int bps, int gen)
{
  __syncthreads();                       // block's stores drained to L2
  if (threadIdx.x == 0) {
    const int s = wi & 7;
    int* A = bar + (g * 8 + s) * 32;
    int* R = bar + (64 + g) * 32;
    int* F = bar + (72 + g * 8 + s) * 32;
    int c = __hip_atomic_fetch_add(A, 1, __ATOMIC_RELEASE, __HIP_MEMORY_SCOPE_AGENT);
    if (c == gen * bps - 1) {                             // last of subleaf
      int r = __hip_atomic_fetch_add(R, 1, __ATOMIC_ACQ_REL, __HIP_MEMORY_SCOPE_AGENT);
      if (r == gen * 8 - 1) {                             // last of group
        for (int s2 = 0; s2 < 8; ++s2)
          __hip_atomic_store(bar + (72 + g * 8 + s2) * 32, gen,
                             __ATOMIC_RELEASE, __HIP_MEMORY_SCOPE_AGENT);
      }
    }
    while (__hip_atomic_load(F, __ATOMIC_RELAXED, __HIP_MEMORY_SCOPE_AGENT) < gen)
      __builtin_amdgcn_s_sleep(4);
    (void)__hip_atomic_load(F, __ATOMIC_ACQUIRE, __HIP_MEMORY_SCOPE_AGENT);
  }
  __syncthreads();
}

// ---------------------------------------------------------------------------
// 256-point Stockham radix-2 FFT in LDS. 256 threads, auto-sorting.
// Result ends in (sAr, sAi). No scaling either direction.
// ---------------------------------------------------------------------------
template<bool INVERSE>
__device__ __forceinline__ void fft256(SharedMem& sh, int t)
{
  float *sr = sh.sAr, *si = sh.sAi, *dr = sh.sBr, *di = sh.sBi;
#pragma unroll
  for (int s = 0; s < 8; ++s) {
    __syncthreads();
    int m  = 1 << s;
    int k  = t & (m - 1);
    int jm = (t >> (s + 1)) << s;
    int i0 = k + jm;
    float c0r = sr[i0],       c0i = si[i0];
    float c1r = sr[i0 + 128], c1i = si[i0 + 128];
    float orr, oii;
    if ((t >> s) & 1) {
      float xr = c0r - c1r, xi = c0i - c1i;
      float wr = sh.twr[jm];
      float wi = INVERSE ? -sh.twi[jm] : sh.twi[jm];
      orr = xr * wr - xi * wi;
      oii = xr * wi + xi * wr;
    } else {
      orr = c0r + c1r;
      oii = c0i + c1i;
    }
    dr[t] = orr; di[t] = oii;
    float* tp;
    tp = sr; sr = dr; dr = tp;
    tp = si; si = di; di = tp;
  }
  __syncthreads();
}

// ---------------------------------------------------------------------------
// Layouts (float2). Spectral state truncated to ky <= 85 (dealias filter
// zeroes ky>85 forever; input has exactly-zero energy beyond |k|~30).
//   u, h : [b][ky][kx]     8*129*256  (rows 86..128 unused)
//   G    : [f][b][ky][x]   4*8*129*256  (rows 86..128 never written/read)
//   NL1  : [b][ky][x]      8*86*256
//   rec  : [r][b][ky][kx]  3*8*129*256  (rows <=85 used; r=0 slab doubles
//                                        as init scratch W1)
// ---------------------------------------------------------------------------

__device__ __forceinline__ void real_item(SharedMem& sh, int t, int b, int x0,
    const float2* __restrict__ G, float2* __restrict__ NL1)
{
  for (int i = t; i < 258; i += 256) {
    int ky = i >> 1, xl = i & 1;
    float ax = 0.f, ay = 0.f, cx = 0.f, cy = 0.f;
    if (ky <= 85) {
      float2 a = G[(((size_t)0 * 8 + b) * 129 + ky) * 256 + x0 + xl];
      float2 c = G[(((size_t)1 * 8 + b) * 129 + ky) * 256 + x0 + xl];
      ax = a.x; ay = a.y; cx = c.x; cy = c.y;
    }
    sh.t0r[ky * 3 + xl] = ax; sh.t0i[ky * 3 + xl] = ay;
    sh.t1r[ky * 3 + xl] = cx; sh.t1i[ky * 3 + xl] = cy;
  }
  __syncthreads();
  const int  kk    = (t <= 128) ? t : 256 - t;
  const bool lower = (t <= 128);
  float vxr[2], vyr[2];
#pragma unroll
  for (int xl = 0; xl < 2; ++xl) {
    float ar = sh.t0r[kk * 3 + xl], ai = sh.t0i[kk * 3 + xl];
    float br = sh.t1r[kk * 3 + xl], bi = sh.t1i[kk * 3 + xl];
    sh.sAr[t] = lower ? (ar - bi) : (ar + bi);   // Z = Hvx + i*Hvy
    sh.sAi[t] = lower ? (ai + br) : (br - ai);
    fft256<true>(sh, t);
    vxr[xl] = sh.sAr[t]; vyr[xl] = sh.sAi[t];
  }
  __syncthreads();
  for (int i = t; i < 258; i += 256) {
    int ky = i >> 1, xl = i & 1;
    float ax = 0.f, ay = 0.f, cx = 0.f, cy = 0.f;
    if (ky <= 85) {
      float2 a = G[(((size_t)2 * 8 + b) * 129 + ky) * 256 + x0 + xl];
      float2 c = G[(((size_t)3 * 8 + b) * 129 + ky) * 256 + x0 + xl];
      ax = a.x; ay = a.y; cx = c.x; cy = c.y;
    }
    sh.t0r[ky * 3 + xl] = ax; sh.t0i[ky * 3 + xl] = ay;
    sh.t1r[ky * 3 + xl] = cx; sh.t1i[ky * 3 + xl] = cy;
  }
  __syncthreads();
  float nl[2];
#pragma unroll
  for (int xl = 0; xl < 2; ++xl) {
    float ar = sh.t0r[kk * 3 + xl], ai = sh.t0i[kk * 3 + xl];
    float br = sh.t1r[kk * 3 + xl], bi = sh.t1i[kk * 3 + xl];
    sh.sAr[t] = lower ? (ar - bi) : (ar + bi);   // Z = Hgx + i*Hgy
    sh.sAi[t] = lower ? (ai + br) : (br - ai);
    fft256<true>(sh, t);
    float gx = sh.sAr[t], gy = sh.sAi[t];
    nl[xl] = -(vxr[xl] * gx + vyr[xl] * gy);
  }
  sh.sAr[t] = nl[0]; sh.sAi[t] = nl[1];
  fft256<false>(sh, t);
  if (t <= 85) {
    int mI = (256 - t) & 255;
    float zr = sh.sAr[t],  zi = sh.sAi[t];
    float wr = sh.sAr[mI], wi = sh.sAi[mI];
    float f0r = 0.5f * (zr + wr), f0i = 0.5f * (zi - wi);
    float f1r = 0.5f * (zi + wi), f1i = 0.5f * (wr - zr);
    NL1[((size_t)b * 86 + t) * 256 + x0]     = make_float2(f0r, f0i);
    NL1[((size_t)b * 86 + t) * 256 + x0 + 1] = make_float2(f1r, f1i);
  }
  __syncthreads();   // protect sAr cross-lane reads before any LDS reuse
}

// ky <= 85 always here.
__device__ __forceinline__ void spectral_item(SharedMem& sh, int t, int b, int ky,
    const float2* __restrict__ NL1, float2* __restrict__ u, float2* __restrict__ h,
    float2* __restrict__ G, float2* __restrict__ rec,
    float beta, float gdt, float mu, bool doUpdate, int recIdx)
{
  const size_t row = ((size_t)b * 129 + ky) * 256;
  float2 uu = u[row + t];
  float ur = uu.x, ui = uu.y;
  const int jx = (t < 128) ? t : t - 256;
  const float k2 = (float)(jx * jx + ky * ky);

  if (doUpdate) {
    float2 nv = NL1[((size_t)b * 86 + ky) * 256 + t];
    sh.sAr[t] = nv.x; sh.sAi[t] = nv.y;
    fft256<false>(sh, t);
    float advr = 0.f, advi = 0.f;
    if (t < 85 || t >= 171) { advr = sh.sAr[t]; advi = sh.sAi[t]; }  // kx filter
    if (t == 0 && ky == 4) {                                         // forcing
      float s_, c_;
      __sincosf(PI_F / 64.0f, &s_, &c_);
      advr -= 131072.0f * c_;
      advi -= 131072.0f * s_;
    }
    float hr = advr, hi = advi;
    if (beta != 0.0f) {
      float2 hh = h[row + t];
      hr += beta * hh.x; hi += beta * hh.y;
    }
    const float lin  = -0.001f * k2 - 0.1f;
    const float anum = 1.0f + mu * lin;
    const float invd = 1.0f / (1.0f - mu * lin);
    ur = (ur * anum + gdt * hr) * invd;
    ui = (ui * anum + gdt * hi) * invd;
    u[row + t] = make_float2(ur, ui);
    h[row + t] = make_float2(hr, hi);
    if (recIdx >= 0)
      rec[((size_t)recIdx * 8 + b) * (129 * 256) + (size_t)ky * 256 + t] = make_float2(ur, ui);
  }

  const float NRM = 1.0f / 65536.0f;
  const float inv_lapnz = (k2 == 0.0f) ? 1.0f : (-1.0f / k2);
  const float urN = ur * NRM, uiN = ui * NRM;
  const float psr = -urN * inv_lapnz, psi_ = -uiN * inv_lapnz;
  const float fjx = (float)jx, fjy = (float)ky;

  sh.sAr[t] = -fjy * psi_; sh.sAi[t] = fjy * psr;        // vx_hat = i*ky*psi
  fft256<true>(sh, t);
  G[(((size_t)0 * 8 + b) * 129 + ky) * 256 + t] = make_float2(sh.sAr[t], sh.sAi[t]);
  sh.sAr[t] = fjx * psi_; sh.sAi[t] = -fjx * psr;        // vy_hat = -i*kx*psi
  fft256<true>(sh, t);
  G[(((size_t)1 * 8 + b) * 129 + ky) * 256 + t] = make_float2(sh.sAr[t], sh.sAi[t]);
  sh.sAr[t] = -fjx * uiN; sh.sAi[t] = fjx * urN;         // gx_hat = i*kx*u
  fft256<true>(sh, t);
  G[(((size_t)2 * 8 + b) * 129 + ky) * 256 + t] = make_float2(sh.sAr[t], sh.sAi[t]);
  sh.sAr[t] = -fjy * uiN; sh.sAi[t] = fjy * urN;         // gy_hat = i*ky*u
  fft256<true>(sh, t);
  G[(((size_t)3 * 8 + b) * 129 + ky) * 256 + t] = make_float2(sh.sAr[t], sh.sAi[t]);
}

// ---------------------------------------------------------------------------
// Persistent kernel: 8 per-batch groups of gsz = gridDim.x/8 blocks; each
// group runs the whole 450-stage solve for its batch with group-local
// barriers. gridDim.x must be a multiple of 64 (any size >= 64 works).
// ---------------------------------------------------------------------------
__global__ __launch_bounds__(256, 4) void k_persist(
    const float* __restrict__ vort, float* __restrict__ out,
    float2* __restrict__ u, float2* __restrict__ h,
    float2* __restrict__ G, float2* __restrict__ NL1, float2* __restrict__ rec,
    int* __restrict__ bar)
{
  const int t   = threadIdx.x;
  const int g   = blockIdx.x & 7;     // batch / group
  const int wi  = blockIdx.x >> 3;    // 0..gsz-1 within group
  const int gsz = gridDim.x >> 3;     // blocks per group
  const int bps = gsz >> 3;           // blocks per subleaf
  int gen = 0;
  __shared__ SharedMem sh;

  if (t < 128) {
    float s_, c_;
    __sincosf(-(2.0f * PI_F / 256.0f) * (float)t, &s_, &c_);
    sh.twr[t] = c_; sh.twi[t] = s_;
  }

  // ---- init: rfft along y for x-rows; W1 = rec r=0 slab (batch g chunk) ----
  float2* W1 = rec + (size_t)g * (129 * 256);
  for (int x = wi; x < 256; x += gsz) {
    sh.sAr[t] = vort[((size_t)g * 256 + x) * 256 + t];
    sh.sAi[t] = 0.0f;
    fft256<false>(sh, t);
    if (t < 129) W1[(size_t)t * 256 + x] = make_float2(sh.sAr[t], sh.sAi[t]);
    __syncthreads();
  }
  group_bar(bar, g, wi, bps, ++gen);

  // ---- init: complex FFT along x for rows ky < 86: W1 -> u ----
  for (int ky = wi; ky < 86; ky += gsz) {
    float2 v = W1[(size_t)ky * 256 + t];
    sh.sAr[t] = v.x; sh.sAi[t] = v.y;
    fft256<false>(sh, t);
    u[((size_t)g * 129 + ky) * 256 + t] = make_float2(sh.sAr[t], sh.sAi[t]);
  }
  group_bar(bar, g, wi, bps, ++gen);

  // ---- prepare G from initial u (no update) ----
  for (int ky = wi; ky < 86; ky += gsz)
    spectral_item(sh, t, g, ky, NL1, u, h, G, rec, 0.f, 0.f, 0.f, false, -1);

  // ---- main loop: 90 steps x 5 RK stages ----
  for (int step = 1; step <= 90; ++step) {
    for (int k = 0; k < 5; ++k) {
      group_bar(bar, g, wi, bps, ++gen);
      for (int w = wi; w < 128; w += gsz)
        real_item(sh, t, g, w * 2, G, NL1);
      group_bar(bar, g, wi, bps, ++gen);
      const int recIdx = (k == 4 && step % 30 == 0) ? (step / 30 - 1) : -1;
      for (int ky = wi; ky < 86; ky += gsz)
        spectral_item(sh, t, g, ky, NL1, u, h, G, rec,
                      c_beta[k], c_gdt[k], c_mu[k], true, recIdx);
    }
  }
  group_bar(bar, g, wi, bps, ++gen);

  // ---- final: inverse col FFT of records (rows <=85): rec -> G scratch ----
  for (int w = wi; w < 258; w += gsz) {
    int r = w / 86, ky = w % 86;
    const size_t row = (((size_t)r * 8 + g) * 129 + ky) * 256;
    float2 v = rec[row + t];
    sh.sAr[t] = v.x; sh.sAi[t] = v.y;
    fft256<true>(sh, t);
    G[row + t] = make_float2(sh.sAr[t], sh.sAi[t]);
  }
  group_bar(bar, g, wi, bps, ++gen);

  // ---- final: paired hermitian inverse row FFT -> real output ----
  const float NRM = 1.0f / 65536.0f;
  for (int w = wi; w < 384; w += gsz) {
    int r = w >> 7, xq = w & 127;
    int x0 = xq * 2;
    for (int i = t; i < 258; i += 256) {
      int ky = i >> 1, xl = i & 1;
      float ax = 0.f, ay = 0.f;
      if (ky <= 85) {
        float2 a = G[(((size_t)r * 8 + g) * 129 + ky) * 256 + x0 + xl];
        ax = a.x; ay = a.y;
      }
      sh.t0r[ky * 3 + xl] = ax; sh.t0i[ky * 3 + xl] = ay;
    }
    __syncthreads();
    const int  kk    = (t <= 128) ? t : 256 - t;
    const bool lower = (t <= 128);
    float ar = sh.t0r[kk * 3 + 0], ai = sh.t0i[kk * 3 + 0];
    float br = sh.t0r[kk * 3 + 1], bi = sh.t0i[kk * 3 + 1];
    sh.sAr[t] = lower ? (ar - bi) : (ar + bi);
    sh.sAi[t] = lower ? (ai + br) : (br - ai);
    fft256<true>(sh, t);
    out[((((size_t)r * 8 + g) * 256) + x0) * 256 + t]     = sh.sAr[t] * NRM;
    out[((((size_t)r * 8 + g) * 256) + x0 + 1) * 256 + t] = sh.sAi[t] * NRM;
    __syncthreads();
  }
}

// ---------------------------------------------------------------------------
extern "C" void kernel_launch(void* const* d_in, const int* in_sizes, int n_in,
                              void* d_out, int out_size, void* d_ws, size_t ws_size,
                              hipStream_t stream)
{
  const float* vort = (const float*)d_in[0];
  float* out = (float*)d_out;

  // workspace carve-up (float2 units); ~19.5 MiB + 17KB barrier
  float2* base = (float2*)d_ws;
  float2* u    = base;                 // 8*129*256   = 264192
  float2* h    = u + 264192;           // 264192
  float2* G    = h + 264192;           // 4*8*129*256 = 1056768
  float2* NL1  = G + 1056768;          // 8*86*256    = 176128
  float2* rec  = NL1 + 176128;         // 3*8*129*256 = 792576
  int*    bar  = (int*)(rec + 792576); // 136 lines * 32 ints

  // zero barrier state before every run (capture-legal)
  hipMemsetAsync(bar, 0, 136 * 32 * sizeof(int), stream);

  // size the grid to what the runtime will accept for a cooperative launch
  int maxPerCU = 0;
  hipOccupancyMaxActiveBlocksPerMultiprocessor(&maxPerCU, k_persist, 256, 0);
  int NBg = maxPerCU * 256;            // 256 CUs on MI355X
  if (NBg <= 0)  NBg = 512;            // defensive fallback
  if (NBg > 1024) NBg = 1024;
  NBg &= ~63;                          // multiple of 64 (8 groups x 8 subleaves)
  if (NBg < 64)  NBg = 64;

  void* args[] = {(void*)&vort, (void*)&out, (void*)&u, (void*)&h,
                  (void*)&G, (void*)&NL1, (void*)&rec, (void*)&bar};
  hipLaunchCooperativeKernel(k_persist, dim3(NBg), dim3(256), args, 0, stream);
}

// Round 6
// 11560.803 us; speedup vs baseline: 7.7168x; 2.3939x over previous
//
#include <hip/hip_runtime.h>
#include <math.h>

#define PI_F 3.14159265358979323846f
typedef unsigned long long u64;

// RK stage constants: beta[k], gdt[k]=GAMMA[k]*DT, mu[k]=0.5*DT*(ALPHA[k+1]-ALPHA[k])
__constant__ float c_beta[5] = {0.0f, -0.4178904745f, -1.192151694643f,
                                -1.697784692471f, -1.514183444257f};
__constant__ float c_gdt[5]  = {1.496590219993e-4f, 3.792103129999e-4f,
                                8.229550293869e-4f, 6.994504559488e-4f,
                                1.530572479681e-4f};
__constant__ float c_mu[5]   = {7.482951099965e-5f, 1.1037096768255e-4f,
                                1.2592740288505e-4f, 1.6801318377015e-4f,
                                2.08589346626e-5f};

struct __align__(128) Line { int v; int pad[31]; };

struct SharedMem {
  float sAr[256], sAi[256], sBr[256], sBi[256];
  float twr[128], twi[128];
  float t0r[387], t0i[387], t1r[387], t1i[387];   // [129][2] tiles, stride 3
};

// ---------------------------------------------------------------------------
// Coherent (L1-bypassing, device-coherence-point) 8B accessors for handoff
// arrays. Relaxed agent atomics: no wbL2/invL2 in their lowering.
// ---------------------------------------------------------------------------
__device__ __forceinline__ float2 ldc(const float2* p)
{
  u64 v = __hip_atomic_load((const u64*)p, __ATOMIC_RELAXED, __HIP_MEMORY_SCOPE_AGENT);
  float2 f; __builtin_memcpy(&f, &v, 8); return f;
}
__device__ __forceinline__ void stc(float2* p, float2 f)
{
  u64 v; __builtin_memcpy(&v, &f, 8);
  __hip_atomic_store((u64*)p, v, __ATOMIC_RELAXED, __HIP_MEMORY_SCOPE_AGENT);
}

// ---------------------------------------------------------------------------
// Barrier: per-block arrival flag (own line) + leader-wave aggregation +
// 8 distributed release lines. fenced=true adds agent release/acquire
// (cross-XCD safe); fenced=false is flag-only (same-L2 groups / coherent
// data path). __syncthreads() before arrival drains each wave's stores
// (compiler emits s_waitcnt vmcnt(0) lgkmcnt(0) before s_barrier).
// ---------------------------------------------------------------------------
__device__ __forceinline__ void bar_sync(Line* arr, Line* rel, int n, int idx,
                                         bool lead, int gen, bool fenced)
{
  const int t = threadIdx.x;
  __syncthreads();
  if (t == 0) {
    __builtin_amdgcn_s_waitcnt(0);
    __builtin_amdgcn_sched_barrier(0);
    if (fenced)
      __hip_atomic_store(&arr[idx].v, gen, __ATOMIC_RELEASE, __HIP_MEMORY_SCOPE_AGENT);
    else
      __hip_atomic_store(&arr[idx].v, gen, __ATOMIC_RELAXED, __HIP_MEMORY_SCOPE_AGENT);
  }
  if (lead && t < 64) {                      // leader block, wave 0 aggregates
    bool done = false;
    while (!done) {
      bool ok = true;
      for (int w = t; w < n; w += 64)
        if (__hip_atomic_load(&arr[w].v, __ATOMIC_RELAXED, __HIP_MEMORY_SCOPE_AGENT) < gen)
          ok = false;
      done = __all(ok);
      if (!done) __builtin_amdgcn_s_sleep(1);
    }
    __builtin_amdgcn_sched_barrier(0);
    if (fenced)
      (void)__hip_atomic_load(&arr[t & 7].v, __ATOMIC_ACQUIRE, __HIP_MEMORY_SCOPE_AGENT);
    if (t < 8) {
      if (fenced)
        __hip_atomic_store(&rel[t].v, gen, __ATOMIC_RELEASE, __HIP_MEMORY_SCOPE_AGENT);
      else
        __hip_atomic_store(&rel[t].v, gen, __ATOMIC_RELAXED, __HIP_MEMORY_SCOPE_AGENT);
    }
  }
  if (t == 0) {
    Line* f = &rel[idx & 7];
    while (__hip_atomic_load(&f->v, __ATOMIC_RELAXED, __HIP_MEMORY_SCOPE_AGENT) < gen)
      __builtin_amdgcn_s_sleep(1);
    if (fenced)
      (void)__hip_atomic_load(&f->v, __ATOMIC_ACQUIRE, __HIP_MEMORY_SCOPE_AGENT);
    __builtin_amdgcn_sched_barrier(0);
  }
  __syncthreads();
}

// ---------------------------------------------------------------------------
// 256-point Stockham radix-2 FFT in LDS. 256 threads, auto-sorting.
// ---------------------------------------------------------------------------
template<bool INVERSE>
__device__ __forceinline__ void fft256(SharedMem& sh, int t)
{
  float *sr = sh.sAr, *si = sh.sAi, *dr = sh.sBr, *di = sh.sBi;
#pragma unroll
  for (int s = 0; s < 8; ++s) {
    __syncthreads();
    int m  = 1 << s;
    int k  = t & (m - 1);
    int jm = (t >> (s + 1)) << s;
    int i0 = k + jm;
    float c0r = sr[i0],       c0i = si[i0];
    float c1r = sr[i0 + 128], c1i = si[i0 + 128];
    float orr, oii;
    if ((t >> s) & 1) {
      float xr = c0r - c1r, xi = c0i - c1i;
      float wr = sh.twr[jm];
      float wi = INVERSE ? -sh.twi[jm] : sh.twi[jm];
      orr = xr * wr - xi * wi;
      oii = xr * wi + xi * wr;
    } else {
      orr = c0r + c1r;
      oii = c0i + c1i;
    }
    dr[t] = orr; di[t] = oii;
    float* tp;
    tp = sr; sr = dr; dr = tp;
    tp = si; si = di; di = tp;
  }
  __syncthreads();
}

// ---------------------------------------------------------------------------
// Layouts (float2). ky truncated to <=85 (dealias zeroes the rest forever).
//   u, h : [b][ky][kx]     8*129*256   (plain cached: same-block reuse)
//   G    : [f][b][ky][x]   4*8*129*256 (coherent handoff)
//   NL1  : [b][ky][x]      8*86*256    (coherent handoff)
//   rec  : [r][b][ky][kx]  3*8*129*256 (coherent; r=0 slab doubles as W1)
// ---------------------------------------------------------------------------

__device__ __forceinline__ void real_item(SharedMem& sh, int t, int b, int x0,
    const float2* __restrict__ G, float2* __restrict__ NL1)
{
  for (int i = t; i < 258; i += 256) {
    int ky = i >> 1, xl = i & 1;
    float ax = 0.f, ay = 0.f, cx = 0.f, cy = 0.f;
    if (ky <= 85) {
      float2 a = ldc(&G[(((size_t)0 * 8 + b) * 129 + ky) * 256 + x0 + xl]);
      float2 c = ldc(&G[(((size_t)1 * 8 + b) * 129 + ky) * 256 + x0 + xl]);
      ax = a.x; ay = a.y; cx = c.x; cy = c.y;
    }
    sh.t0r[ky * 3 + xl] = ax; sh.t0i[ky * 3 + xl] = ay;
    sh.t1r[ky * 3 + xl] = cx; sh.t1i[ky * 3 + xl] = cy;
  }
  __syncthreads();
  const int  kk    = (t <= 128) ? t : 256 - t;
  const bool lower = (t <= 128);
  float vxr[2], vyr[2];
#pragma unroll
  for (int xl = 0; xl < 2; ++xl) {
    float ar = sh.t0r[kk * 3 + xl], ai = sh.t0i[kk * 3 + xl];
    float br = sh.t1r[kk * 3 + xl], bi = sh.t1i[kk * 3 + xl];
    sh.sAr[t] = lower ? (ar - bi) : (ar + bi);   // Z = Hvx + i*Hvy
    sh.sAi[t] = lower ? (ai + br) : (br - ai);
    fft256<true>(sh, t);
    vxr[xl] = sh.sAr[t]; vyr[xl] = sh.sAi[t];
  }
  __syncthreads();
  for (int i = t; i < 258; i += 256) {
    int ky = i >> 1, xl = i & 1;
    float ax = 0.f, ay = 0.f, cx = 0.f, cy = 0.f;
    if (ky <= 85) {
      float2 a = ldc(&G[(((size_t)2 * 8 + b) * 129 + ky) * 256 + x0 + xl]);
      float2 c = ldc(&G[(((size_t)3 * 8 + b) * 129 + ky) * 256 + x0 + xl]);
      ax = a.x; ay = a.y; cx = c.x; cy = c.y;
    }
    sh.t0r[ky * 3 + xl] = ax; sh.t0i[ky * 3 + xl] = ay;
    sh.t1r[ky * 3 + xl] = cx; sh.t1i[ky * 3 + xl] = cy;
  }
  __syncthreads();
  float nl[2];
#pragma unroll
  for (int xl = 0; xl < 2; ++xl) {
    float ar = sh.t0r[kk * 3 + xl], ai = sh.t0i[kk * 3 + xl];
    float br = sh.t1r[kk * 3 + xl], bi = sh.t1i[kk * 3 + xl];
    sh.sAr[t] = lower ? (ar - bi) : (ar + bi);   // Z = Hgx + i*Hgy
    sh.sAi[t] = lower ? (ai + br) : (br - ai);
    fft256<true>(sh, t);
    float gx = sh.sAr[t], gy = sh.sAi[t];
    nl[xl] = -(vxr[xl] * gx + vyr[xl] * gy);
  }
  sh.sAr[t] = nl[0]; sh.sAi[t] = nl[1];
  fft256<false>(sh, t);
  if (t <= 85) {
    int mI = (256 - t) & 255;
    float zr = sh.sAr[t],  zi = sh.sAi[t];
    float wr = sh.sAr[mI], wi = sh.sAi[mI];
    float f0r = 0.5f * (zr + wr), f0i = 0.5f * (zi - wi);
    float f1r = 0.5f * (zi + wi), f1i = 0.5f * (wr - zr);
    stc(&NL1[((size_t)b * 86 + t) * 256 + x0],     make_float2(f0r, f0i));
    stc(&NL1[((size_t)b * 86 + t) * 256 + x0 + 1], make_float2(f1r, f1i));
  }
  __syncthreads();   // protect cross-lane sAr reads before any LDS reuse
}

// ky <= 85 always here.
__device__ __forceinline__ void spectral_item(SharedMem& sh, int t, int b, int ky,
    const float2* __restrict__ NL1, float2* __restrict__ u, float2* __restrict__ h,
    float2* __restrict__ G, float2* __restrict__ rec,
    float beta, float gdt, float mu, bool doUpdate, int recIdx)
{
  const size_t row = ((size_t)b * 129 + ky) * 256;
  float2 uu = u[row + t];
  float ur = uu.x, ui = uu.y;
  const int jx = (t < 128) ? t : t - 256;
  const float k2 = (float)(jx * jx + ky * ky);

  if (doUpdate) {
    float2 nv = ldc(&NL1[((size_t)b * 86 + ky) * 256 + t]);
    sh.sAr[t] = nv.x; sh.sAi[t] = nv.y;
    fft256<false>(sh, t);
    float advr = 0.f, advi = 0.f;
    if (t < 85 || t >= 171) { advr = sh.sAr[t]; advi = sh.sAi[t]; }  // kx filter
    if (t == 0 && ky == 4) {                                         // forcing
      float s_, c_;
      __sincosf(PI_F / 64.0f, &s_, &c_);
      advr -= 131072.0f * c_;
      advi -= 131072.0f * s_;
    }
    float hr = advr, hi = advi;
    if (beta != 0.0f) {
      float2 hh = h[row + t];
      hr += beta * hh.x; hi += beta * hh.y;
    }
    const float lin  = -0.001f * k2 - 0.1f;
    const float anum = 1.0f + mu * lin;
    const float invd = 1.0f / (1.0f - mu * lin);
    ur = (ur * anum + gdt * hr) * invd;
    ui = (ui * anum + gdt * hi) * invd;
    u[row + t] = make_float2(ur, ui);
    h[row + t] = make_float2(hr, hi);
    if (recIdx >= 0)
      stc(&rec[((size_t)recIdx * 8 + b) * (129 * 256) + (size_t)ky * 256 + t],
          make_float2(ur, ui));
  }

  const float NRM = 1.0f / 65536.0f;
  const float inv_lapnz = (k2 == 0.0f) ? 1.0f : (-1.0f / k2);
  const float urN = ur * NRM, uiN = ui * NRM;
  const float psr = -urN * inv_lapnz, psi_ = -uiN * inv_lapnz;
  const float fjx = (float)jx, fjy = (float)ky;

  sh.sAr[t] = -fjy * psi_; sh.sAi[t] = fjy * psr;        // vx_hat = i*ky*psi
  fft256<true>(sh, t);
  stc(&G[(((size_t)0 * 8 + b) * 129 + ky) * 256 + t], make_float2(sh.sAr[t], sh.sAi[t]));
  sh.sAr[t] = fjx * psi_; sh.sAi[t] = -fjx * psr;        // vy_hat = -i*kx*psi
  fft256<true>(sh, t);
  stc(&G[(((size_t)1 * 8 + b) * 129 + ky) * 256 + t], make_float2(sh.sAr[t], sh.sAi[t]));
  sh.sAr[t] = -fjx * uiN; sh.sAi[t] = fjx * urN;         // gx_hat = i*kx*u
  fft256<true>(sh, t);
  stc(&G[(((size_t)2 * 8 + b) * 129 + ky) * 256 + t], make_float2(sh.sAr[t], sh.sAi[t]));
  sh.sAr[t] = -fjy * uiN; sh.sAi[t] = fjy * urN;         // gy_hat = i*ky*u
  fft256<true>(sh, t);
  stc(&G[(((size_t)3 * 8 + b) * 129 + ky) * 256 + t], make_float2(sh.sAr[t], sh.sAi[t]));
}

// ---------------------------------------------------------------------------
// Persistent kernel. Blocks self-organize into 8 groups by physical XCD id
// (read via s_getreg HW_REG_XCC_ID); group g serves batch g with runtime
// worker count nW. Fast path: flag-only barriers + coherent data accessors
// (all handoff L2/coherence-point local). If registration looks inconsistent,
// fall back to blockIdx grouping with fully fenced barriers (== round-5).
// ---------------------------------------------------------------------------
__global__ __launch_bounds__(256, 4) void k_persist(
    const float* __restrict__ vort, float* __restrict__ out,
    float2* __restrict__ u, float2* __restrict__ h,
    float2* __restrict__ G, float2* __restrict__ NL1, float2* __restrict__ rec,
    Line* __restrict__ bar)
{
  const int t   = threadIdx.x;
  const int blk = blockIdx.x;
  const int NBg = gridDim.x;

  Line* arrGrid = bar;                  // 1024 lines
  Line* relGrid = bar + 1024;           // 8
  Line* arrGrpA = bar + 1032;           // 8 * 256
  Line* relGrpA = bar + 1032 + 2048;    // 8 * 8
  Line* regL    = bar + 1032 + 2048 + 64; // 16 lines: per-XCD counters

  __shared__ SharedMem sh;
  __shared__ int s_x, s_wi;

  if (t < 128) {
    float s_, c_;
    __sincosf(-(2.0f * PI_F / 256.0f) * (float)t, &s_, &c_);
    sh.twr[t] = c_; sh.twi[t] = s_;
  }

  // ---- registration: claim a worker slot on this block's physical XCD ----
  if (t == 0) {
    int x;
    asm volatile("s_getreg_b32 %0, hwreg(HW_REG_XCC_ID)" : "=s"(x));
    x &= 15;
    s_x  = x;
    s_wi = atomicAdd(&regL[x].v, 1);
  }
  __syncthreads();

  int gen = 0;
  // one fenced grid barrier: registration + init ordering
  bar_sync(arrGrid, relGrid, NBg, blk, blk == 0, ++gen, true);

  // ---- decide mapping (uniform across grid) ----
  int tot = 0, mn = 1 << 30, mx = 0;
  for (int i = 0; i < 8; ++i) {
    int c = regL[i].v;
    tot += c; mn = min(mn, c); mx = max(mx, c);
  }
  const bool fast = (tot == NBg) && (mn > 0) && (mx <= 256);
  int g, wi, nW;
  if (fast) { g = s_x;     wi = s_wi;     nW = regL[g].v; }
  else      { g = blk & 7; wi = blk >> 3; nW = NBg >> 3;  }
  Line* arr = arrGrpA + g * 256;
  Line* rel = relGrpA + g * 8;
  const bool fenced = !fast;
  const bool lead   = (wi == 0);

  // ---- init: rfft along y for batch g's x-rows; W1 = rec r=0 slab ----
  float2* W1 = rec + (size_t)g * (129 * 256);
  for (int x = wi; x < 256; x += nW) {
    sh.sAr[t] = vort[((size_t)g * 256 + x) * 256 + t];
    sh.sAi[t] = 0.0f;
    fft256<false>(sh, t);
    if (t < 129) stc(&W1[(size_t)t * 256 + x], make_float2(sh.sAr[t], sh.sAi[t]));
    __syncthreads();
  }
  bar_sync(arr, rel, nW, wi, lead, ++gen, fenced);

  // ---- init: col FFT (W1 -> u), then prepare G (same block: no bar) ----
  for (int ky = wi; ky < 86; ky += nW) {
    float2 v = ldc(&W1[(size_t)ky * 256 + t]);
    sh.sAr[t] = v.x; sh.sAi[t] = v.y;
    fft256<false>(sh, t);
    u[((size_t)g * 129 + ky) * 256 + t] = make_float2(sh.sAr[t], sh.sAi[t]);
  }
  for (int ky = wi; ky < 86; ky += nW)
    spectral_item(sh, t, g, ky, NL1, u, h, G, rec, 0.f, 0.f, 0.f, false, -1);

  // ---- main loop: 90 steps x 5 RK stages ----
  for (int step = 1; step <= 90; ++step) {
    for (int k = 0; k < 5; ++k) {
      bar_sync(arr, rel, nW, wi, lead, ++gen, fenced);
      for (int w = wi; w < 128; w += nW)
        real_item(sh, t, g, w * 2, G, NL1);
      bar_sync(arr, rel, nW, wi, lead, ++gen, fenced);
      const int recIdx = (k == 4 && step % 30 == 0) ? (step / 30 - 1) : -1;
      for (int ky = wi; ky < 86; ky += nW)
        spectral_item(sh, t, g, ky, NL1, u, h, G, rec,
                      c_beta[k], c_gdt[k], c_mu[k], true, recIdx);
    }
  }
  bar_sync(arr, rel, nW, wi, lead, ++gen, fenced);

  // ---- final: inverse col FFT of records (rows <86): rec -> G scratch ----
  for (int w = wi; w < 258; w += nW) {
    int r = w / 86, ky = w % 86;
    const size_t row = (((size_t)r * 8 + g) * 129 + ky) * 256;
    float2 v = ldc(&rec[row + t]);
    sh.sAr[t] = v.x; sh.sAi[t] = v.y;
    fft256<true>(sh, t);
    stc(&G[row + t], make_float2(sh.sAr[t], sh.sAi[t]));
  }
  bar_sync(arr, rel, nW, wi, lead, ++gen, fenced);

  // ---- final: paired hermitian inverse row FFT -> real output ----
  const float NRM = 1.0f / 65536.0f;
  for (int w = wi; w < 384; w += nW) {
    int r = w >> 7, xq = w & 127;
    int x0 = xq * 2;
    for (int i = t; i < 258; i += 256) {
      int ky = i >> 1, xl = i & 1;
      float ax = 0.f, ay = 0.f;
      if (ky <= 85) {
        float2 a = ldc(&G[(((size_t)r * 8 + g) * 129 + ky) * 256 + x0 + xl]);
        ax = a.x; ay = a.y;
      }
      sh.t0r[ky * 3 + xl] = ax; sh.t0i[ky * 3 + xl] = ay;
    }
    __syncthreads();
    const int  kk    = (t <= 128) ? t : 256 - t;
    const bool lower = (t <= 128);
    float ar = sh.t0r[kk * 3 + 0], ai = sh.t0i[kk * 3 + 0];
    float br = sh.t0r[kk * 3 + 1], bi = sh.t0i[kk * 3 + 1];
    sh.sAr[t] = lower ? (ar - bi) : (ar + bi);
    sh.sAi[t] = lower ? (ai + br) : (br - ai);
    fft256<true>(sh, t);
    out[((((size_t)r * 8 + g) * 256) + x0) * 256 + t]     = sh.sAr[t] * NRM;
    out[((((size_t)r * 8 + g) * 256) + x0 + 1) * 256 + t] = sh.sAi[t] * NRM;
    __syncthreads();
  }
}

// ---------------------------------------------------------------------------
extern "C" void kernel_launch(void* const* d_in, const int* in_sizes, int n_in,
                              void* d_out, int out_size, void* d_ws, size_t ws_size,
                              hipStream_t stream)
{
  const float* vort = (const float*)d_in[0];
  float* out = (float*)d_out;

  // workspace carve-up (float2 units); ~19.5 MiB data + ~400 KiB barrier
  float2* base = (float2*)d_ws;
  float2* u    = base;                 // 8*129*256   = 264192
  float2* h    = u + 264192;           // 264192
  float2* G    = h + 264192;           // 4*8*129*256 = 1056768
  float2* NL1  = G + 1056768;          // 8*86*256    = 176128
  float2* rec  = NL1 + 176128;         // 3*8*129*256 = 792576
  Line*   bar  = (Line*)(rec + 792576);
  const int nLines = 1024 + 8 + 2048 + 64 + 16;   // 3160 lines

  // zero barrier + registration state before every run (capture-legal)
  hipMemsetAsync(bar, 0, (size_t)nLines * sizeof(Line), stream);

  int maxPerCU = 0;
  hipOccupancyMaxActiveBlocksPerMultiprocessor(&maxPerCU, k_persist, 256, 0);
  int NBg = maxPerCU * 256;            // 256 CUs on MI355X
  if (NBg <= 0)  NBg = 512;
  if (NBg > 1024) NBg = 1024;
  NBg &= ~63;                          // multiple of 64
  if (NBg < 64)  NBg = 64;

  void* args[] = {(void*)&vort, (void*)&out, (void*)&u, (void*)&h,
                  (void*)&G, (void*)&NL1, (void*)&rec, (void*)&bar};
  hipError_t e = hipLaunchCooperativeKernel(k_persist, dim3(NBg), dim3(256),
                                            args, 0, stream);
  if (e != hipSuccess) {
    // co-residency still guaranteed by the occupancy-derived grid size
    hipLaunchKernelGGL(k_persist, dim3(NBg), dim3(256), 0, stream,
                       vort, out, u, h, G, NL1, rec, bar);
  }
}